// Round 6
// baseline (293.529 us; speedup 1.0000x reference)
//
#include <hip/hip_runtime.h>
#include <hip/hip_bf16.h>
#include <math.h>

typedef __bf16 bf16_t;
typedef bf16_t bf16x8 __attribute__((ext_vector_type(8)));
typedef float f32x4 __attribute__((ext_vector_type(4)));

#define BB 4
#define SS 2048
#define HH 16
#define DMODEL 1024
#define DHEAD 64
#define QSCALE 0.18033688011112042f   // 0.125 * log2(e): scores*log2e folded into Q

__device__ inline unsigned short f2bf(float f) {
    union { __hip_bfloat16 h; unsigned short u; } cvt;
    cvt.h = __float2bfloat16(f);
    return cvt.u;
}

// pack two floats' bf16 truncations into one dword: low16=bf16(lo), high16=bf16(hi)
__device__ __forceinline__ unsigned pack_bf2(float lo, float hi) {
    unsigned a = __builtin_bit_cast(unsigned, lo);
    unsigned b = __builtin_bit_cast(unsigned, hi);
    return __builtin_amdgcn_perm(b, a, 0x07060302);
}

// async global->LDS, 16B per lane. LDS dest = wave-uniform base + lane*16.
__device__ __forceinline__ void gll16(const unsigned short* g, unsigned short* l) {
    __builtin_amdgcn_global_load_lds(
        (const __attribute__((address_space(1))) unsigned int*)(g),
        (__attribute__((address_space(3))) unsigned int*)(l), 16, 0, 0);
}

// ---------------- pack kernels ----------------

__global__ void pack_x(const float* __restrict__ x, unsigned short* __restrict__ xb) {
    int i = blockIdx.x * 256 + threadIdx.x;
    const float4 v = ((const float4*)x)[i];
    unsigned short o[4] = { f2bf(v.x), f2bf(v.y), f2bf(v.z), f2bf(v.w) };
    *(uint2*)(xb + 4 * (size_t)i) = *(uint2*)o;
}

// LDS-tiled transposing weight pack: both global sides coalesced.
// bid<768: W_{Q,K,V}[h][m][d] -> qkvT[n=mat*1024+h*64+d][k=m]
// else:    W_O[h][dh][m]      -> woT [n=m][k=h*64+dh]
__global__ __launch_bounds__(256) void pack_w(
    const float* __restrict__ wq, const float* __restrict__ wk, const float* __restrict__ wv,
    const float* __restrict__ wo, unsigned short* __restrict__ qkvT, unsigned short* __restrict__ woT)
{
    __shared__ unsigned short tile[64 * 72];
    const int t = threadIdx.x;
    const int bid = blockIdx.x;
    const int r = t >> 2;
    const int c4 = (t & 3) * 16;
    if (bid < 768) {
        const int mat = bid >> 8;
        const int rem = bid & 255;
        const int h = rem >> 4;
        const int m0 = (rem & 15) * 64;
        const float* w = (mat == 0) ? wq : (mat == 1) ? wk : wv;
        const float* src = w + ((size_t)h << 16) + (size_t)(m0 + r) * 64 + c4;
#pragma unroll
        for (int k2 = 0; k2 < 4; k2++) {
            float4 v = *(const float4*)(src + k2 * 4);
            tile[(c4 + k2 * 4 + 0) * 72 + r] = f2bf(v.x);   // tile[d][m]
            tile[(c4 + k2 * 4 + 1) * 72 + r] = f2bf(v.y);
            tile[(c4 + k2 * 4 + 2) * 72 + r] = f2bf(v.z);
            tile[(c4 + k2 * 4 + 3) * 72 + r] = f2bf(v.w);
        }
        __syncthreads();
        const int d = t >> 2;
        const int rq = (t & 3) * 16;
        unsigned short* dst = qkvT + (size_t)(mat * 1024 + h * 64 + d) * 1024 + m0 + rq;
        *(uint4*)(dst)     = *(const uint4*)(tile + d * 72 + rq);
        *(uint4*)(dst + 8) = *(const uint4*)(tile + d * 72 + rq + 8);
    } else {
        const int bid2 = bid - 768;
        const int h = bid2 >> 4;
        const int m0 = (bid2 & 15) * 64;
        const float* src = wo + ((size_t)h << 16) + (size_t)r * 1024 + m0 + c4;
#pragma unroll
        for (int k2 = 0; k2 < 4; k2++) {
            float4 v = *(const float4*)(src + k2 * 4);
            tile[(c4 + k2 * 4 + 0) * 72 + r] = f2bf(v.x);   // tile[m][dh]
            tile[(c4 + k2 * 4 + 1) * 72 + r] = f2bf(v.y);
            tile[(c4 + k2 * 4 + 2) * 72 + r] = f2bf(v.z);
            tile[(c4 + k2 * 4 + 3) * 72 + r] = f2bf(v.w);
        }
        __syncthreads();
        const int m = t >> 2;
        const int dq = (t & 3) * 16;
        unsigned short* dst = woT + (size_t)(m0 + m) * 1024 + h * 64 + dq;
        *(uint4*)(dst)     = *(const uint4*)(tile + m * 72 + dq);
        *(uint4*)(dst + 8) = *(const uint4*)(tile + m * 72 + dq + 8);
    }
}

// ---------------- GEMM 1 (m97 structure): 128x128 tile, global_load_lds ----------------
// qkv = x @ WqkvT^T + bias.  Q (pre-scaled by 0.125*log2e), K -> [B,H,S,64]
// (swapped-operand MFMA, coalesced stores); V -> transposed [B,H,64,S].
// 1D grid swizzled so all 24 n-blocks of an m-tile share an XCD (x-tile L2 reuse).

__global__ __launch_bounds__(256) void gemm_qkv(
    const unsigned short* __restrict__ xb,    // [8192][1024]
    const unsigned short* __restrict__ wT,    // [3072][1024]
    const float* __restrict__ bq, const float* __restrict__ bk, const float* __restrict__ bv,
    unsigned short* __restrict__ qws, unsigned short* __restrict__ kws,
    unsigned short* __restrict__ vtw)         // [64][64][2048]
{
    __shared__ __align__(16) unsigned short lA[128 * 32];
    __shared__ __align__(16) unsigned short lB[128 * 32];
    const int t = threadIdx.x;
    const int lane = t & 63;
    const int w = t >> 6;
    const int quad = lane >> 4;
    const int l15 = lane & 15;
    const int bid = blockIdx.x;
    const int mb = (bid & 7) + ((bid / 192) << 3);   // xcd = bid%8 = mb&7
    const int nb = (bid >> 3) % 24;
    const int n0 = nb * 128;
    const int m0 = mb * 128;
    const int wm = (w >> 1) * 64;
    const int wn = (w & 1) * 64;
    const int mat = n0 >> 10;

    f32x4 acc[4][4] = {};

    const int srow = w * 16 + (lane >> 2);
    const int scol = (lane & 3) * 8;
    const unsigned short* Ag0 = xb + (size_t)(m0 + srow) * 1024 + scol;
    const unsigned short* Ag1 = Ag0 + (size_t)64 * 1024;
    const unsigned short* Bg0 = wT + (size_t)(n0 + srow) * 1024 + scol;
    const unsigned short* Bg1 = Bg0 + (size_t)64 * 1024;
    unsigned short* lA0 = lA + (w * 16) * 32;
    unsigned short* lA1 = lA + (64 + w * 16) * 32;
    unsigned short* lB0 = lB + (w * 16) * 32;
    unsigned short* lB1 = lB + (64 + w * 16) * 32;

    if (mat != 2) {
        for (int kt = 0; kt < 1024; kt += 32) {
            __syncthreads();
            gll16(Ag0 + kt, lA0);
            gll16(Ag1 + kt, lA1);
            gll16(Bg0 + kt, lB0);
            gll16(Bg1 + kt, lB1);
            __syncthreads();
            bf16x8 af[4], bfr[4];
#pragma unroll
            for (int i = 0; i < 4; i++) {
                af[i]  = *(const bf16x8*)(lA + (wm + i * 16 + l15) * 32 + quad * 8);
                bfr[i] = *(const bf16x8*)(lB + (wn + i * 16 + l15) * 32 + quad * 8);
            }
#pragma unroll
            for (int i = 0; i < 4; i++)
#pragma unroll
                for (int j = 0; j < 4; j++)
                    acc[i][j] = __builtin_amdgcn_mfma_f32_16x16x32_bf16(bfr[j], af[i], acc[i][j], 0, 0, 0);
        }
        const int b = m0 >> 11;
        const float* bias_p = (mat == 0) ? bq : bk;
        unsigned short* dst = (mat == 0) ? qws : kws;
        const float qscale = (mat == 0) ? QSCALE : 1.0f;
#pragma unroll
        for (int j = 0; j < 4; j++) {
            const int noff = wn + j * 16 + quad * 4;
            const int hglob = ((n0 & 1023) >> 6) + (noff >> 6);
            const int dbase = noff & 63;
            const float4 bv4 = *(const float4*)(bias_p + hglob * 64 + dbase);
            const float bias_r[4] = { bv4.x, bv4.y, bv4.z, bv4.w };
#pragma unroll
            for (int i = 0; i < 4; i++) {
                const int s = (m0 & 2047) + wm + i * 16 + l15;
                unsigned short pk[4];
#pragma unroll
                for (int r = 0; r < 4; r++) pk[r] = f2bf((acc[i][j][r] + bias_r[r]) * qscale);
                *(uint2*)(dst + (size_t)((b * 16 + hglob) * 2048 + s) * 64 + dbase) = *(uint2*)pk;
            }
        }
    } else {
        for (int kt = 0; kt < 1024; kt += 32) {
            __syncthreads();
            gll16(Ag0 + kt, lA0);
            gll16(Ag1 + kt, lA1);
            gll16(Bg0 + kt, lB0);
            gll16(Bg1 + kt, lB1);
            __syncthreads();
            bf16x8 af[4], bfr[4];
#pragma unroll
            for (int i = 0; i < 4; i++) {
                af[i]  = *(const bf16x8*)(lA + (wm + i * 16 + l15) * 32 + quad * 8);
                bfr[i] = *(const bf16x8*)(lB + (wn + i * 16 + l15) * 32 + quad * 8);
            }
#pragma unroll
            for (int i = 0; i < 4; i++)
#pragma unroll
                for (int j = 0; j < 4; j++)
                    acc[i][j] = __builtin_amdgcn_mfma_f32_16x16x32_bf16(af[i], bfr[j], acc[i][j], 0, 0, 0);
        }
        const int b = m0 >> 11;
#pragma unroll
        for (int j = 0; j < 4; j++) {
            const int n1 = (n0 & 1023) + wn + j * 16 + l15;
            const int h = n1 >> 6, d = n1 & 63;
            const float bias = bv[h * 64 + d];
#pragma unroll
            for (int i = 0; i < 4; i++) {
                const int s0 = (m0 & 2047) + wm + i * 16 + quad * 4;
                unsigned short pk[4];
#pragma unroll
                for (int r = 0; r < 4; r++) pk[r] = f2bf(acc[i][j][r] + bias);
                *(uint2*)(vtw + ((size_t)(b * 16 + h) * 64 + d) * 2048 + s0) = *(uint2*)pk;
            }
        }
    }
}

// ---------------- attention v6: waves split KEYS; barrier-free K-loop ----------------
// Block = 64 q (shared), wave w owns 32-key chunks c==w (mod 4) in a private LDS
// arena (Ks 32x72, Vs [d][key] 64x32 via gll16, Ps 16x40). Partial O^T / lsum
// merged across waves at the end via LDS tree. Scores transposed (A=K, B=Q).

#define AR_SZ 9984

__global__ __launch_bounds__(256) void attn6(
    const unsigned short* __restrict__ qws,   // pre-scaled by 0.125*log2e
    const unsigned short* __restrict__ kws,
    const unsigned short* __restrict__ vtw,   // [bh][64][2048]
    unsigned short* __restrict__ zb)          // [8192][1024], col = h*64+d
{
    __shared__ __align__(16) unsigned char smem[4 * AR_SZ];
    const int t = threadIdx.x;
    const int lane = t & 63;
    const int w = t >> 6;
    const int quad = lane >> 4;
    const int l15 = lane & 15;

    const int qt = 31 - (blockIdx.x >> 6);   // longest blocks first
    const int bh = blockIdx.x & 63;          // bh%8 -> XCD: K/V L2 locality
    const int q0 = qt * 64;
    const size_t base = (size_t)bh * SS * DHEAD;
    const unsigned short* Q = qws + base;
    const unsigned short* K = kws + base;
    const unsigned short* Vt = vtw + base;

    unsigned short* Ks = (unsigned short*)(smem + w * AR_SZ);          // [32 key][72]
    unsigned short* Vs = (unsigned short*)(smem + w * AR_SZ + 4608);   // [64 d][32 key]
    unsigned short* Pw = (unsigned short*)(smem + w * AR_SZ + 8704);   // [16 q][40 key]

    // Q B-frags for all 64 q (n=q, k=d)
    bf16x8 qf[4][2];
#pragma unroll
    for (int i = 0; i < 4; i++) {
        const unsigned short* qp = Q + (size_t)(q0 + i * 16 + l15) * 64 + quad * 8;
        qf[i][0] = *(const bf16x8*)qp;
        qf[i][1] = *(const bf16x8*)(qp + 32);
    }

    f32x4 o[4][4] = {};            // [q-subtile][d-subtile]: row=d, col=q(l15)
    f32x4 lsum = {0.f, 0.f, 0.f, 0.f};

    const int nch = 2 * qt + 2;
    const int krow = lane >> 1;
    const int kcol = (lane & 1) * 32;

    for (int c = w; c < nch; c += 4) {
        const int kb = c * 32;
        // V: [d][32key] linear via gll16 (lane i of call g -> d=g*16+(i>>2), oct i&3)
#pragma unroll
        for (int g = 0; g < 4; g++)
            gll16(Vt + (size_t)(g * 16 + (lane >> 2)) * 2048 + kb + (lane & 3) * 8, Vs + g * 512);
        // K: per-lane staged, padded stride 72
        {
            const unsigned short* kp = K + (size_t)(kb + krow) * 64 + kcol;
            uint4 a0 = *(const uint4*)(kp);
            uint4 a1 = *(const uint4*)(kp + 8);
            uint4 a2 = *(const uint4*)(kp + 16);
            uint4 a3 = *(const uint4*)(kp + 24);
            unsigned short* kd = Ks + krow * 72 + kcol;
            *(uint4*)(kd)      = a0;
            *(uint4*)(kd + 8)  = a1;
            *(uint4*)(kd + 16) = a2;
            *(uint4*)(kd + 24) = a3;
        }
        asm volatile("s_waitcnt vmcnt(0) lgkmcnt(0)" ::: "memory");

        bf16x8 kf[2][2];
#pragma unroll
        for (int ks = 0; ks < 2; ks++) {
            kf[ks][0] = *(const bf16x8*)(Ks + (ks * 16 + l15) * 72 + quad * 8);
            kf[ks][1] = *(const bf16x8*)(Ks + (ks * 16 + l15) * 72 + 32 + quad * 8);
        }
        bf16x8 vf[4];
#pragma unroll
        for (int dt = 0; dt < 4; dt++)
            vf[dt] = *(const bf16x8*)(Vs + (dt * 16 + l15) * 32 + quad * 8);

        const bool edge = (kb + 31 > q0);
#pragma unroll
        for (int qs = 0; qs < 4; qs++) {
            if (edge && kb > q0 + qs * 16 + 15) continue;   // subtile fully masked
            f32x4 s0 = {}, s1 = {};
            s0 = __builtin_amdgcn_mfma_f32_16x16x32_bf16(kf[0][0], qf[qs][0], s0, 0, 0, 0);
            s0 = __builtin_amdgcn_mfma_f32_16x16x32_bf16(kf[0][1], qf[qs][1], s0, 0, 0, 0);
            s1 = __builtin_amdgcn_mfma_f32_16x16x32_bf16(kf[1][0], qf[qs][0], s1, 0, 0, 0);
            s1 = __builtin_amdgcn_mfma_f32_16x16x32_bf16(kf[1][1], qf[qs][1], s1, 0, 0, 0);
            float p[8];
            if (edge) {
                const int qg = q0 + qs * 16 + l15;
#pragma unroll
                for (int r = 0; r < 4; r++) {
                    p[r]     = (kb + quad * 4 + r      > qg) ? 0.f : exp2f(s0[r]);
                    p[4 + r] = (kb + 16 + quad * 4 + r > qg) ? 0.f : exp2f(s1[r]);
                }
            } else {
#pragma unroll
                for (int r = 0; r < 4; r++) { p[r] = exp2f(s0[r]); p[4 + r] = exp2f(s1[r]); }
            }
            lsum[qs] += p[0] + p[1] + p[2] + p[3] + p[4] + p[5] + p[6] + p[7];
            uint2 d0, d1;
            d0.x = pack_bf2(p[0], p[1]); d0.y = pack_bf2(p[2], p[3]);
            d1.x = pack_bf2(p[4], p[5]); d1.y = pack_bf2(p[6], p[7]);
            *(uint2*)(Pw + l15 * 40 + quad * 4)      = d0;   // keys quad*4+0..3
            *(uint2*)(Pw + l15 * 40 + 16 + quad * 4) = d1;   // keys 16+quad*4+0..3
            asm volatile("s_waitcnt lgkmcnt(0)" ::: "memory");
            bf16x8 pf = *(const bf16x8*)(Pw + l15 * 40 + quad * 8);
#pragma unroll
            for (int dt = 0; dt < 4; dt++)
                o[qs][dt] = __builtin_amdgcn_mfma_f32_16x16x32_bf16(vf[dt], pf, o[qs][dt], 0, 0, 0);
            asm volatile("s_waitcnt lgkmcnt(0)" ::: "memory");  // pf read retired before overwrite
        }
    }

    // cross-wave reduction: waves 1,3 -> regions; 0,2 add; 2 -> region0; 0 adds.
    float* R0 = (float*)(smem);
    float* R1 = (float*)(smem + 17408);
    __syncthreads();
    if (w & 1) {
        float* R = (w == 1) ? R0 : R1;
#pragma unroll
        for (int i = 0; i < 4; i++)
#pragma unroll
            for (int j = 0; j < 4; j++)
                *(f32x4*)(R + ((i * 4 + j) * 64 + lane) * 4) = o[i][j];
        *(f32x4*)(R + 4096 + lane * 4) = lsum;
    }
    __syncthreads();
    if (!(w & 1)) {
        float* R = (w == 0) ? R0 : R1;
#pragma unroll
        for (int i = 0; i < 4; i++)
#pragma unroll
            for (int j = 0; j < 4; j++)
                o[i][j] += *(const f32x4*)(R + ((i * 4 + j) * 64 + lane) * 4);
        lsum += *(const f32x4*)(R + 4096 + lane * 4);
    }
    __syncthreads();
    if (w == 2) {
#pragma unroll
        for (int i = 0; i < 4; i++)
#pragma unroll
            for (int j = 0; j < 4; j++)
                *(f32x4*)(R0 + ((i * 4 + j) * 64 + lane) * 4) = o[i][j];
        *(f32x4*)(R0 + 4096 + lane * 4) = lsum;
    }
    __syncthreads();
    if (w == 0) {
#pragma unroll
        for (int i = 0; i < 4; i++)
#pragma unroll
            for (int j = 0; j < 4; j++)
                o[i][j] += *(const f32x4*)(R0 + ((i * 4 + j) * 64 + lane) * 4);
        lsum += *(const f32x4*)(R0 + 4096 + lane * 4);
        const int b = bh >> 4, h = bh & 15;
#pragma unroll
        for (int i = 0; i < 4; i++) {
            float v = lsum[i];
            v += __shfl_xor(v, 16);
            v += __shfl_xor(v, 32);
            const float inv = 1.0f / v;
            const int q = q0 + i * 16 + l15;
            unsigned short* zr = zb + (size_t)(b * 2048 + q) * 1024 + h * 64 + quad * 4;
#pragma unroll
            for (int dt = 0; dt < 4; dt++) {
                unsigned short pk[4];
#pragma unroll
                for (int r = 0; r < 4; r++) pk[r] = f2bf(o[i][dt][r] * inv);
                *(uint2*)(zr + dt * 16) = *(uint2*)pk;
            }
        }
    }
}

// ---------------- GEMM 2 (m97 structure, swapped operands): out = z @ WoT^T + bO ----------------

__global__ __launch_bounds__(256) void gemm_out(
    const unsigned short* __restrict__ zb,    // [8192][1024]
    const unsigned short* __restrict__ wT,    // [1024][1024]
    const float* __restrict__ bo,
    float* __restrict__ out)
{
    __shared__ __align__(16) unsigned short lA[128 * 32];
    __shared__ __align__(16) unsigned short lB[128 * 32];
    const int t = threadIdx.x;
    const int lane = t & 63;
    const int w = t >> 6;
    const int quad = lane >> 4;
    const int l15 = lane & 15;
    const int bid = blockIdx.x;
    const int mb = (bid & 7) + ((bid >> 6) << 3);
    const int nb = (bid >> 3) & 7;
    const int n0 = nb * 128;
    const int m0 = mb * 128;
    const int wm = (w >> 1) * 64;
    const int wn = (w & 1) * 64;

    f32x4 acc[4][4] = {};

    const int srow = w * 16 + (lane >> 2);
    const int scol = (lane & 3) * 8;
    const unsigned short* Ag0 = zb + (size_t)(m0 + srow) * 1024 + scol;
    const unsigned short* Ag1 = Ag0 + (size_t)64 * 1024;
    const unsigned short* Bg0 = wT + (size_t)(n0 + srow) * 1024 + scol;
    const unsigned short* Bg1 = Bg0 + (size_t)64 * 1024;
    unsigned short* lA0 = lA + (w * 16) * 32;
    unsigned short* lA1 = lA + (64 + w * 16) * 32;
    unsigned short* lB0 = lB + (w * 16) * 32;
    unsigned short* lB1 = lB + (64 + w * 16) * 32;

    for (int kt = 0; kt < 1024; kt += 32) {
        __syncthreads();
        gll16(Ag0 + kt, lA0);
        gll16(Ag1 + kt, lA1);
        gll16(Bg0 + kt, lB0);
        gll16(Bg1 + kt, lB1);
        __syncthreads();
        bf16x8 af[4], bfr[4];
#pragma unroll
        for (int i = 0; i < 4; i++) {
            af[i]  = *(const bf16x8*)(lA + (wm + i * 16 + l15) * 32 + quad * 8);
            bfr[i] = *(const bf16x8*)(lB + (wn + i * 16 + l15) * 32 + quad * 8);
        }
#pragma unroll
        for (int i = 0; i < 4; i++)
#pragma unroll
            for (int j = 0; j < 4; j++)
                acc[i][j] = __builtin_amdgcn_mfma_f32_16x16x32_bf16(bfr[j], af[i], acc[i][j], 0, 0, 0);
    }

#pragma unroll
    for (int j = 0; j < 4; j++) {
        const int nbase = n0 + wn + j * 16 + quad * 4;
        const float4 bv4 = *(const float4*)(bo + nbase);
#pragma unroll
        for (int i = 0; i < 4; i++) {
            const int s = m0 + wm + i * 16 + l15;
            float4 v;
            v.x = acc[i][j][0] + bv4.x;
            v.y = acc[i][j][1] + bv4.y;
            v.z = acc[i][j][2] + bv4.z;
            v.w = acc[i][j][3] + bv4.w;
            *(float4*)(out + (size_t)s * 1024 + nbase) = v;
        }
    }
}

// ---------------- launch ----------------

extern "C" void kernel_launch(void* const* d_in, const int* in_sizes, int n_in,
                              void* d_out, int out_size, void* d_ws, size_t ws_size,
                              hipStream_t stream) {
    const float* x  = (const float*)d_in[0];
    const float* WQ = (const float*)d_in[1];
    const float* WK = (const float*)d_in[2];
    const float* WV = (const float*)d_in[3];
    const float* WO = (const float*)d_in[4];
    const float* bQ = (const float*)d_in[5];
    const float* bK = (const float*)d_in[6];
    const float* bV = (const float*)d_in[7];
    const float* bO = (const float*)d_in[8];
    float* out = (float*)d_out;

    char* ws = (char*)d_ws;
    unsigned short* xb   = (unsigned short*)ws;                   // 16 MB (reused as zbuf)
    unsigned short* wqkv = (unsigned short*)(ws + (16u << 20));   // 6 MB
    unsigned short* woT  = (unsigned short*)(ws + (22u << 20));   // 2 MB
    unsigned short* qws  = (unsigned short*)(ws + (24u << 20));   // 16 MB
    unsigned short* kws  = (unsigned short*)(ws + (40u << 20));   // 16 MB
    unsigned short* vtw  = (unsigned short*)(ws + (56u << 20));   // 16 MB, [bh][64][2048]
    unsigned short* zbuf = xb;                                    // x dead after gemm_qkv

    pack_x<<<8192, 256, 0, stream>>>(x, xb);
    pack_w<<<1024, 256, 0, stream>>>(WQ, WK, WV, WO, wqkv, woT);
    gemm_qkv<<<1536, 256, 0, stream>>>(xb, wqkv, bQ, bK, bV, qws, kws, vtw);
    attn6<<<2048, 256, 0, stream>>>(qws, kws, vtw, zbuf);
    gemm_out<<<512, 256, 0, stream>>>(zbuf, woT, bO, out);
}